// Round 1
// baseline (1706.216 us; speedup 1.0000x reference)
//
#include <hip/hip_runtime.h>

#define KC 1024      // num codes
#define DD 256       // embedding dim
#define NROWS 65536  // 16*4096
#define BM 64        // rows per block
#define XSTRIDE 260  // 256 + 4 pad (2-way LDS conflict max)
#define WSTRIDE 36   // 32 + 4 pad
#define NT 256

// ---------------- |e_k|^2 (double-accurate, rounded to f32) ----------------
__global__ void se_kernel(const float* __restrict__ W, float* __restrict__ se) {
    int k = blockIdx.x;
    int lane = threadIdx.x;
    float4 v = reinterpret_cast<const float4*>(W + (size_t)k * DD)[lane];
    double s = (double)v.x * v.x + (double)v.y * v.y + (double)v.z * v.z + (double)v.w * v.w;
    for (int m = 32; m >= 1; m >>= 1) s += __shfl_xor(s, m, 64);
    if (lane == 0) se[k] = (float)s;
}

// ---------------- main: scores + argmin + quantize + loss + scatter ----------------
__global__ __launch_bounds__(NT) void vq_main(
    const float* __restrict__ X, const float* __restrict__ W,
    const float* __restrict__ se, float* __restrict__ out_q,
    float* __restrict__ out_idx, float* __restrict__ counts,
    float* __restrict__ emb, double* __restrict__ loss_acc)
{
    __shared__ __align__(16) float xs[BM * XSTRIDE];   // 66560 B
    __shared__ __align__(16) float wsh[64 * WSTRIDE];  // 9216 B
    __shared__ float sxs[BM];
    __shared__ double sxp[BM * 4];
    __shared__ int argidx[BM];
    __shared__ double lred[4];

    const int tid = threadIdx.x;
    const int row0 = blockIdx.x * BM;

    // stage X tile (coalesced float4)
    for (int p = 0; p < 16; ++p) {
        int i = p * NT + tid;
        int r = i >> 6, c4 = i & 63;
        float4 v = reinterpret_cast<const float4*>(X + (size_t)(row0 + r) * DD)[c4];
        *reinterpret_cast<float4*>(&xs[r * XSTRIDE + c4 * 4]) = v;
    }
    __syncthreads();

    // |x|^2 per row in double (4 partials per row)
    {
        int r = tid >> 2, q = tid & 3;
        const float* xr = &xs[r * XSTRIDE + q * 64];
        double s = 0.0;
        for (int d = 0; d < 64; ++d) { double xv = (double)xr[d]; s += xv * xv; }
        sxp[r * 4 + q] = s;
    }
    __syncthreads();
    if (tid < BM) {
        double s = sxp[tid * 4] + sxp[tid * 4 + 1] + sxp[tid * 4 + 2] + sxp[tid * 4 + 3];
        sxs[tid] = (float)s;
    }
    __syncthreads();

    const int rg = tid >> 4, cg = tid & 15;
    float best[4];
    int bidx[4];
#pragma unroll
    for (int i = 0; i < 4; ++i) { best[i] = 3.4e38f; bidx[i] = 0; }

    for (int ct = 0; ct < 16; ++ct) {
        float acc[4][4];
#pragma unroll
        for (int i = 0; i < 4; ++i)
#pragma unroll
            for (int j = 0; j < 4; ++j) acc[i][j] = 0.0f;

        for (int dc = 0; dc < 8; ++dc) {
            __syncthreads();  // protect wsh from previous readers
#pragma unroll
            for (int p = 0; p < 2; ++p) {
                int i = p * NT + tid;       // 0..511
                int r = i >> 3, f = i & 7;  // 64 rows x 8 float4
                float4 v = reinterpret_cast<const float4*>(
                    W + (size_t)(ct * 64 + r) * DD + dc * 32)[f];
                *reinterpret_cast<float4*>(&wsh[r * WSTRIDE + f * 4]) = v;
            }
            __syncthreads();
#pragma unroll
            for (int d4 = 0; d4 < 8; ++d4) {
                float4 xv[4], wv[4];
#pragma unroll
                for (int i = 0; i < 4; ++i)
                    xv[i] = *reinterpret_cast<const float4*>(
                        &xs[(rg * 4 + i) * XSTRIDE + dc * 32 + d4 * 4]);
#pragma unroll
                for (int j = 0; j < 4; ++j)
                    wv[j] = *reinterpret_cast<const float4*>(
                        &wsh[(cg * 4 + j) * WSTRIDE + d4 * 4]);
#pragma unroll
                for (int i = 0; i < 4; ++i)
#pragma unroll
                    for (int j = 0; j < 4; ++j) {
                        acc[i][j] += xv[i].x * wv[j].x;
                        acc[i][j] += xv[i].y * wv[j].y;
                        acc[i][j] += xv[i].z * wv[j].z;
                        acc[i][j] += xv[i].w * wv[j].w;
                    }
            }
        }
        // running argmin; mimic ref rounding: fl(fl(sx+se) - fl(2*dot))
#pragma unroll
        for (int j = 0; j < 4; ++j) {
            int code = ct * 64 + cg * 4 + j;
            float sec = se[code];
#pragma unroll
            for (int i = 0; i < 4; ++i) {
                float t1 = __fadd_rn(sxs[rg * 4 + i], sec);
                float s = __fsub_rn(t1, __fmul_rn(2.0f, acc[i][j]));
                if (s < best[i] || (s == best[i] && code < bidx[i])) {
                    best[i] = s;
                    bidx[i] = code;
                }
            }
        }
    }

    // reduce (val,idx) across the 16 cg lanes (same wave, aligned group)
#pragma unroll
    for (int i = 0; i < 4; ++i) {
        float v = best[i];
        int ix = bidx[i];
        for (int m = 8; m >= 1; m >>= 1) {
            float ov = __shfl_xor(v, m, 64);
            int oi = __shfl_xor(ix, m, 64);
            if (ov < v || (ov == v && oi < ix)) { v = ov; ix = oi; }
        }
        if (cg == 0) argidx[rg * 4 + i] = ix;
    }
    __syncthreads();

    if (tid < BM) {
        atomicAdd(&counts[argidx[tid]], 1.0f);
        out_idx[row0 + tid] = (float)argidx[tid];
    }

    // quantized out + loss + emb scatter: 4 threads per row, 64 elems each
    double lacc = 0.0;
    {
        int r = tid >> 2, part = tid & 3;
        int k = argidx[r];
        const float* wr = W + (size_t)k * DD;
        float* o = out_q + (size_t)(row0 + r) * DD;
        const float* xr = &xs[r * XSTRIDE];
        float* er = emb + (size_t)k * DD;
        for (int it = 0; it < 16; ++it) {
            int d = (it * 4 + part) * 4;
            float4 q = *reinterpret_cast<const float4*>(wr + d);
            float4 x = *reinterpret_cast<const float4*>(xr + d);
            float4 df, o4;
            df.x = q.x - x.x; df.y = q.y - x.y; df.z = q.z - x.z; df.w = q.w - x.w;
            o4.x = x.x + df.x; o4.y = x.y + df.y; o4.z = x.z + df.z; o4.w = x.w + df.w;
            *reinterpret_cast<float4*>(o + d) = o4;
            lacc += (double)df.x * df.x + (double)df.y * df.y +
                    (double)df.z * df.z + (double)df.w * df.w;
            atomicAdd(er + d + 0, x.x);
            atomicAdd(er + d + 1, x.y);
            atomicAdd(er + d + 2, x.z);
            atomicAdd(er + d + 3, x.w);
        }
    }
    for (int m = 32; m >= 1; m >>= 1) lacc += __shfl_xor(lacc, m, 64);
    if ((tid & 63) == 0) lred[tid >> 6] = lacc;
    __syncthreads();
    if (tid == 0) atomicAdd(loss_acc, lred[0] + lred[1] + lred[2] + lred[3]);
}

// ---------------- finalize 1: new_cluster_size, n, loss ----------------
__global__ void fin1(const float* __restrict__ ema_cs, float* __restrict__ ncs_buf,
                     const double* __restrict__ loss_acc, float* __restrict__ out_loss,
                     float* __restrict__ n_out)
{
    __shared__ float red[1024];
    int t = threadIdx.x;
    const float OM = (float)(1.0 - 0.99);
    float cnt = ncs_buf[t];  // accumulated counts
    float ncs = __fadd_rn(__fmul_rn(0.99f, ema_cs[t]), __fmul_rn(OM, cnt));
    ncs_buf[t] = ncs;
    red[t] = ncs;
    __syncthreads();
    for (int s = 512; s >= 1; s >>= 1) {
        if (t < s) red[t] += red[t + s];
        __syncthreads();
    }
    if (t == 0) {
        n_out[0] = red[0];
        float el = (float)(loss_acc[0] / 16777216.0);
        out_loss[0] = __fadd_rn(el, __fmul_rn(0.25f, el));
    }
}

// ---------------- finalize 2: new_embedding_avg, new_weight ----------------
__global__ __launch_bounds__(256) void fin2(const float* __restrict__ ema_avg,
                                            float* __restrict__ avg_buf,  // holds emb_sum, becomes new_avg
                                            const float* __restrict__ ncs,
                                            const float* __restrict__ n_ptr,
                                            float* __restrict__ out_w)
{
    int k = blockIdx.x, d = threadIdx.x;
    const float OM = (float)(1.0 - 0.99);
    const float KEPS = (float)(1024.0 * 1e-5);
    size_t i = (size_t)k * DD + d;
    float avg = __fadd_rn(__fmul_rn(0.99f, ema_avg[i]), __fmul_rn(OM, avg_buf[i]));
    float n = n_ptr[0];
    float cs = __fmul_rn(__fdiv_rn(__fadd_rn(ncs[k], 1e-5f), __fadd_rn(n, KEPS)), n);
    avg_buf[i] = avg;
    out_w[i] = __fdiv_rn(avg, cs);
}

extern "C" void kernel_launch(void* const* d_in, const int* in_sizes, int n_in,
                              void* d_out, int out_size, void* d_ws, size_t ws_size,
                              hipStream_t stream) {
    const float* X = (const float*)d_in[0];
    const float* W = (const float*)d_in[1];
    const float* ema_cs = (const float*)d_in[2];
    const float* ema_avg = (const float*)d_in[3];

    float* out = (float*)d_out;
    float* out_q    = out;                  // 16777216
    float* out_loss = out + 16777216;       // 1
    float* out_idx  = out + 16777217;       // 65536
    float* out_w    = out + 16842753;       // 262144
    float* out_ncs  = out + 17104897;       // 1024 (used as counts accumulator first)
    float* out_avg  = out + 17105921;       // 262144 (used as emb_sum accumulator first)

    float* se = (float*)d_ws;                          // 1024 f32
    float* n_ptr = (float*)((char*)d_ws + 4096);       // 1 f32
    double* loss = (double*)((char*)d_ws + 4096 + 16); // 1 f64

    // zero the accumulators (graph-capture safe)
    hipMemsetAsync(out_ncs, 0, 1024 * sizeof(float), stream);
    hipMemsetAsync(out_avg, 0, 262144 * sizeof(float), stream);
    hipMemsetAsync(loss, 0, sizeof(double), stream);

    se_kernel<<<KC, 64, 0, stream>>>(W, se);
    vq_main<<<NROWS / BM, NT, 0, stream>>>(X, W, se, out_q, out_idx, out_ncs, out_avg, loss);
    fin1<<<1, 1024, 0, stream>>>(ema_cs, out_ncs, loss, out_loss, n_ptr);
    fin2<<<KC, 256, 0, stream>>>(ema_avg, out_avg, out_ncs, n_ptr, out_w);
}

// Round 3
// 856.059 us; speedup vs baseline: 1.9931x; 1.9931x over previous
//
#include <hip/hip_runtime.h>

#define KC 1024
#define DD 256
#define NROWS 65536
#define BM 64    // rows per block
#define NT 256   // 4 waves
#define RESCUE_EPS 0.01f

typedef __bf16 bf16x8 __attribute__((ext_vector_type(8)));
typedef float f32x4 __attribute__((ext_vector_type(4)));

__device__ __forceinline__ unsigned short f32_bf16_rne(float f) {
    unsigned int u = __float_as_uint(f);
    u += 0x7fffu + ((u >> 16) & 1u);
    return (unsigned short)(u >> 16);
}
__device__ __forceinline__ float bf16_f32(unsigned short h) {
    return __uint_as_float(((unsigned int)h) << 16);
}

// ---------------- |e_k|^2 (double-accurate, rounded to f32) ----------------
__global__ void se_kernel(const float* __restrict__ W, float* __restrict__ se) {
    int k = blockIdx.x;
    int lane = threadIdx.x;
    float4 v = reinterpret_cast<const float4*>(W + (size_t)k * DD)[lane];
    double s = (double)v.x * v.x + (double)v.y * v.y + (double)v.z * v.z + (double)v.w * v.w;
    for (int m = 32; m >= 1; m >>= 1) s += __shfl_xor(s, m, 64);
    if (lane == 0) se[k] = (float)s;
}

// ---------------- W fp32 -> bf16 hi/lo ----------------
__global__ __launch_bounds__(256) void wconv(const float* __restrict__ W,
                                             unsigned short* __restrict__ wh,
                                             unsigned short* __restrict__ wl) {
    int i = blockIdx.x * 256 + threadIdx.x;
    float x = W[i];
    unsigned short h = f32_bf16_rne(x);
    float r = x - bf16_f32(h);
    wh[i] = h;
    wl[i] = f32_bf16_rne(r);
}

// ---------------- main: MFMA scores + best/second argmin + flagging ----------------
__global__ __launch_bounds__(NT, 2) void vq_mfma(
    const float* __restrict__ X,
    const unsigned short* __restrict__ wh, const unsigned short* __restrict__ wl,
    const float* __restrict__ se, float* __restrict__ out_idx,
    int* __restrict__ idx_int, float* __restrict__ sx_out,
    int* __restrict__ flags, int* __restrict__ count)
{
    __shared__ __align__(16) unsigned short xh[BM * DD];   // 32 KB (16B-swizzled)
    __shared__ __align__(16) unsigned short xl[BM * DD];   // 32 KB
    __shared__ float sxp[BM * 32];                         // 8 KB
    __shared__ float sxs[BM];
    __shared__ float wb1[4][BM];
    __shared__ float wb2[4][BM];
    __shared__ int wi1[4][BM];

    const int tid = threadIdx.x;
    const int row0 = blockIdx.x * BM;

    // ---- stage X: fp32 -> bf16 hi/lo into swizzled LDS; partial |x|^2 ----
    for (int i = 0; i < 8; ++i) {
        int j = i * NT + tid;          // 0..2047
        int row = j >> 5, c8 = j & 31; // 8-float chunk
        const float4* xp = reinterpret_cast<const float4*>(X + (size_t)(row0 + row) * DD + c8 * 8);
        float4 a = xp[0], b = xp[1];
        float v[8] = {a.x, a.y, a.z, a.w, b.x, b.y, b.z, b.w};
        unsigned short h[8], l[8];
        double ss = 0.0;
#pragma unroll
        for (int q = 0; q < 8; ++q) {
            h[q] = f32_bf16_rne(v[q]);
            l[q] = f32_bf16_rne(v[q] - bf16_f32(h[q]));
            ss += (double)v[q] * v[q];
        }
        int slot = (row * 32 + c8) ^ (row & 7);
        *reinterpret_cast<uint4*>(&xh[slot * 8]) = *reinterpret_cast<uint4*>(h);
        *reinterpret_cast<uint4*>(&xl[slot * 8]) = *reinterpret_cast<uint4*>(l);
        sxp[row * 32 + c8] = (float)ss;
    }
    __syncthreads();
    if (tid < BM) {
        double s = 0.0;
        for (int c = 0; c < 32; ++c) s += (double)sxp[tid * 32 + c];
        sxs[tid] = (float)s;
    }
    __syncthreads();

    const int w = tid >> 6;       // wave 0..3
    const int lane = tid & 63;
    const int m = lane & 15;      // code-within-16 / A-row-within-16
    const int g = lane >> 4;      // k-group / D-row-quarter

    float b1[4][4], b2[4][4];
    int i1[4][4];
#pragma unroll
    for (int rt = 0; rt < 4; ++rt)
#pragma unroll
        for (int j = 0; j < 4; ++j) { b1[rt][j] = 3.4e38f; b2[rt][j] = 3.4e38f; i1[rt][j] = 0; }

    for (int ct = 0; ct < 16; ++ct) {
        const int mycode = ct * 64 + w * 16 + m;
        float sec = se[mycode];

        f32x4 acc[4];
#pragma unroll
        for (int rt = 0; rt < 4; ++rt) acc[rt] = (f32x4){0.f, 0.f, 0.f, 0.f};

#pragma unroll
        for (int ks = 0; ks < 8; ++ks) {
            const size_t wo = (size_t)mycode * DD + ks * 32 + g * 8;
            bf16x8 bh = *reinterpret_cast<const bf16x8*>(wh + wo);
            bf16x8 bl = *reinterpret_cast<const bf16x8*>(wl + wo);
#pragma unroll
            for (int rt = 0; rt < 4; ++rt) {
                int r = rt * 16 + m;
                int slot = (r * 32 + ks * 4 + g) ^ (r & 7);
                bf16x8 ah = *reinterpret_cast<const bf16x8*>(&xh[slot * 8]);
                bf16x8 al = *reinterpret_cast<const bf16x8*>(&xl[slot * 8]);
                acc[rt] = __builtin_amdgcn_mfma_f32_16x16x32_bf16(ah, bh, acc[rt], 0, 0, 0);
                acc[rt] = __builtin_amdgcn_mfma_f32_16x16x32_bf16(al, bh, acc[rt], 0, 0, 0);
                acc[rt] = __builtin_amdgcn_mfma_f32_16x16x32_bf16(ah, bl, acc[rt], 0, 0, 0);
            }
        }
#pragma unroll
        for (int rt = 0; rt < 4; ++rt)
#pragma unroll
            for (int j = 0; j < 4; ++j) {
                int row = rt * 16 + g * 4 + j;
                float s = __fsub_rn(__fadd_rn(sxs[row], sec), __fmul_rn(2.0f, acc[rt][j]));
                if (s < b1[rt][j]) {
                    b2[rt][j] = b1[rt][j];
                    b1[rt][j] = s;
                    i1[rt][j] = mycode;
                } else if (s < b2[rt][j]) {
                    b2[rt][j] = s;
                }
            }
    }

    // cross-lane (code-dim) reduce of (b1,i1,b2) within wave
#pragma unroll
    for (int rt = 0; rt < 4; ++rt)
#pragma unroll
        for (int j = 0; j < 4; ++j) {
            float v1 = b1[rt][j], v2 = b2[rt][j];
            int ix = i1[rt][j];
            for (int mm = 1; mm < 16; mm <<= 1) {
                float ov1 = __shfl_xor(v1, mm, 64);
                int oi = __shfl_xor(ix, mm, 64);
                float ov2 = __shfl_xor(v2, mm, 64);
                float nv2 = fminf(fminf(v2, ov2), fmaxf(v1, ov1));
                if (ov1 < v1 || (ov1 == v1 && oi < ix)) { v1 = ov1; ix = oi; }
                v2 = nv2;
            }
            if (m == 0) {
                int row = rt * 16 + g * 4 + j;
                wb1[w][row] = v1;
                wb2[w][row] = v2;
                wi1[w][row] = ix;
            }
        }
    __syncthreads();

    if (tid < BM) {
        float v1 = wb1[0][tid], v2 = wb2[0][tid];
        int ix = wi1[0][tid];
#pragma unroll
        for (int ww = 1; ww < 4; ++ww) {
            float ov1 = wb1[ww][tid], ov2 = wb2[ww][tid];
            int oi = wi1[ww][tid];
            float nv2 = fminf(fminf(v2, ov2), fmaxf(v1, ov1));
            if (ov1 < v1 || (ov1 == v1 && oi < ix)) { v1 = ov1; ix = oi; }
            v2 = nv2;
        }
        int row = row0 + tid;
        idx_int[row] = ix;
        out_idx[row] = (float)ix;
        sx_out[row] = sxs[tid];
        if (v2 - v1 < RESCUE_EPS) {
            int p = atomicAdd(count, 1);
            flags[p] = row;
        }
    }
}

// ---------------- rescue: exact-fp32 re-argmin for near-tie rows ----------------
__global__ __launch_bounds__(256) void rescue(
    const float* __restrict__ X, const float* __restrict__ W,
    const float* __restrict__ se, const float* __restrict__ sx,
    const int* __restrict__ flags, const int* __restrict__ count,
    int* __restrict__ idx_int, float* __restrict__ out_idx)
{
    __shared__ __align__(16) float xs[DD];
    __shared__ float rv[256];
    __shared__ int ri[256];
    const int t = threadIdx.x;
    const int n = count[0];
    for (int i = blockIdx.x; i < n; i += gridDim.x) {
        const int row = flags[i];
        if (t < 64) {
            float4 v = reinterpret_cast<const float4*>(X + (size_t)row * DD)[t];
            *reinterpret_cast<float4*>(&xs[t * 4]) = v;
        }
        __syncthreads();
        const float sxr = sx[row];
        float best = 3.4e38f;
        int bi = 0;
#pragma unroll
        for (int cc = 0; cc < 4; ++cc) {
            int c = cc * 256 + t;
            const float* wr = W + (size_t)c * DD;
            float acc = 0.0f;
            for (int d = 0; d < DD; ++d) acc = fmaf(xs[d], wr[d], acc);
            float s = __fsub_rn(__fadd_rn(sxr, se[c]), __fmul_rn(2.0f, acc));
            if (s < best || (s == best && c < bi)) { best = s; bi = c; }
        }
        rv[t] = best; ri[t] = bi;
        __syncthreads();
        for (int sft = 128; sft >= 1; sft >>= 1) {
            if (t < sft) {
                float ov = rv[t + sft];
                int oi = ri[t + sft];
                if (ov < rv[t] || (ov == rv[t] && oi < ri[t])) { rv[t] = ov; ri[t] = oi; }
            }
            __syncthreads();
        }
        if (t == 0) {
            idx_int[row] = ri[0];
            out_idx[row] = (float)ri[0];
        }
        __syncthreads();
    }
}

// ---------------- epilogue: quantize + loss + counts + emb scatter ----------------
__global__ __launch_bounds__(256) void epilogue(
    const float* __restrict__ X, const float* __restrict__ W,
    const int* __restrict__ idx_int, float* __restrict__ out_q,
    float* __restrict__ counts, float* __restrict__ emb,
    double* __restrict__ loss_acc)
{
    __shared__ double lred[4];
    const int tid = threadIdx.x;
    const int row0 = blockIdx.x * BM;
    const int r = tid >> 2, part = tid & 3;
    const int row = row0 + r;
    const int k = idx_int[row];
    if (part == 0) atomicAdd(&counts[k], 1.0f);

    const float* wr = W + (size_t)k * DD;
    const float* xr = X + (size_t)row * DD;
    float* o = out_q + (size_t)row * DD;
    float* er = emb + (size_t)k * DD;
    double lacc = 0.0;
    for (int it = 0; it < 16; ++it) {
        int d = (it * 4 + part) * 4;
        float4 q = *reinterpret_cast<const float4*>(wr + d);
        float4 x = *reinterpret_cast<const float4*>(xr + d);
        float4 df, o4;
        df.x = q.x - x.x; df.y = q.y - x.y; df.z = q.z - x.z; df.w = q.w - x.w;
        o4.x = x.x + df.x; o4.y = x.y + df.y; o4.z = x.z + df.z; o4.w = x.w + df.w;
        *reinterpret_cast<float4*>(o + d) = o4;
        lacc += (double)df.x * df.x + (double)df.y * df.y +
                (double)df.z * df.z + (double)df.w * df.w;
        atomicAdd(er + d + 0, x.x);
        atomicAdd(er + d + 1, x.y);
        atomicAdd(er + d + 2, x.z);
        atomicAdd(er + d + 3, x.w);
    }
    for (int mm = 32; mm >= 1; mm >>= 1) lacc += __shfl_xor(lacc, mm, 64);
    if ((tid & 63) == 0) lred[tid >> 6] = lacc;
    __syncthreads();
    if (tid == 0) atomicAdd(loss_acc, lred[0] + lred[1] + lred[2] + lred[3]);
}

// ---------------- finalize 1 ----------------
__global__ void fin1(const float* __restrict__ ema_cs, float* __restrict__ ncs_buf,
                     const double* __restrict__ loss_acc, float* __restrict__ out_loss,
                     float* __restrict__ n_out)
{
    __shared__ float red[1024];
    int t = threadIdx.x;
    const float OM = (float)(1.0 - 0.99);
    float cnt = ncs_buf[t];
    float ncs = __fadd_rn(__fmul_rn(0.99f, ema_cs[t]), __fmul_rn(OM, cnt));
    ncs_buf[t] = ncs;
    red[t] = ncs;
    __syncthreads();
    for (int s = 512; s >= 1; s >>= 1) {
        if (t < s) red[t] += red[t + s];
        __syncthreads();
    }
    if (t == 0) {
        n_out[0] = red[0];
        float el = (float)(loss_acc[0] / 16777216.0);
        out_loss[0] = __fadd_rn(el, __fmul_rn(0.25f, el));
    }
}

// ---------------- finalize 2 ----------------
__global__ __launch_bounds__(256) void fin2(const float* __restrict__ ema_avg,
                                            float* __restrict__ avg_buf,
                                            const float* __restrict__ ncs,
                                            const float* __restrict__ n_ptr,
                                            float* __restrict__ out_w)
{
    int k = blockIdx.x, d = threadIdx.x;
    const float OM = (float)(1.0 - 0.99);
    const float KEPS = (float)(1024.0 * 1e-5);
    size_t i = (size_t)k * DD + d;
    float avg = __fadd_rn(__fmul_rn(0.99f, ema_avg[i]), __fmul_rn(OM, avg_buf[i]));
    float n = n_ptr[0];
    float cs = __fmul_rn(__fdiv_rn(__fadd_rn(ncs[k], 1e-5f), __fadd_rn(n, KEPS)), n);
    avg_buf[i] = avg;
    out_w[i] = __fdiv_rn(avg, cs);
}

extern "C" void kernel_launch(void* const* d_in, const int* in_sizes, int n_in,
                              void* d_out, int out_size, void* d_ws, size_t ws_size,
                              hipStream_t stream) {
    const float* X = (const float*)d_in[0];
    const float* W = (const float*)d_in[1];
    const float* ema_cs = (const float*)d_in[2];
    const float* ema_avg = (const float*)d_in[3];

    float* out = (float*)d_out;
    float* out_q    = out;                  // 16777216
    float* out_loss = out + 16777216;       // 1
    float* out_idx  = out + 16777217;       // 65536
    float* out_w    = out + 16842753;       // 262144
    float* out_ncs  = out + 17104897;       // 1024  (counts accumulator first)
    float* out_avg  = out + 17105921;       // 262144 (emb_sum accumulator first)

    char* ws = (char*)d_ws;
    float* se      = (float*)(ws + 0);               // 4 KB
    float* n_ptr   = (float*)(ws + 4096);
    double* loss   = (double*)(ws + 4112);
    int*   count   = (int*)(ws + 4128);
    unsigned short* wh = (unsigned short*)(ws + 8192);           // 512 KB
    unsigned short* wl = (unsigned short*)(ws + 8192 + 524288);  // 512 KB
    float* sx      = (float*)(ws + 1056768);         // 256 KB
    int*   idx_int = (int*)(ws + 1318912);           // 256 KB
    int*   flags   = (int*)(ws + 1581056);           // 256 KB

    hipMemsetAsync(out_ncs, 0, 1024 * sizeof(float), stream);
    hipMemsetAsync(out_avg, 0, 262144 * sizeof(float), stream);
    hipMemsetAsync(loss, 0, sizeof(double), stream);
    hipMemsetAsync(count, 0, sizeof(int), stream);

    se_kernel<<<KC, 64, 0, stream>>>(W, se);
    wconv<<<KC, 256, 0, stream>>>(W, wh, wl);
    vq_mfma<<<NROWS / BM, NT, 0, stream>>>(X, wh, wl, se, out_idx, idx_int, sx, flags, count);
    rescue<<<1024, 256, 0, stream>>>(X, W, se, sx, flags, count, idx_int, out_idx);
    epilogue<<<NROWS / BM, NT, 0, stream>>>(X, W, idx_int, out_q, out_ncs, out_avg, loss);
    fin1<<<1, 1024, 0, stream>>>(ema_cs, out_ncs, loss, out_loss, n_ptr);
    fin2<<<KC, 256, 0, stream>>>(ema_avg, out_avg, out_ncs, n_ptr, out_w);
}